// Round 2
// baseline (112.450 us; speedup 1.0000x reference)
//
#include <hip/hip_runtime.h>

// Polyphase resample up=3 down=2, N=2097152, L=129 taps, start=(L-1)/2=64.
// out[3j+0] = 3 * sum_i x[21+2j-i] * h[1+3i]   (i in [0,43))
// out[3j+1] = 3 * sum_i x[22+2j-i] * h[0+3i]
// out[3j+2] = 3 * sum_i x[22+2j-i] * h[2+3i]
// (formula verified: R1/R2 passed with absmax 0.25)
//
// R4 post-mortem of R3: single 50-word register window is the right
// structure, but __launch_bounds__(256,4) only sets a MIN waves/EU; LLVM
// targeted 8 waves/EU (64-VGPR budget) and spilled ~80 words/thread to
// scratch (FETCH 77MB, WRITE 98MB vs ideal 8.4/12.6MB). The grid only
// supplies 4 waves/SIMD, so that occupancy was unusable anyway.
// Fix: amdgpu_waves_per_eu(4,4) pins the range -> 128-VGPR budget, no
// spill, all-resident occupancy.

#define N_SIG   2097152
#define L_FILT  129
#define NTAPS   43
#define G       4            // output groups per thread (12 outputs)
#define BLK     256
#define GROUPS_PER_BLK (BLK * G)             // 1024 groups -> 3072 outputs/block
#define TILE_Q  2112                         // logical tile words (covers q in [0,2093))
#define TILE_P  (TILE_Q + TILE_Q / 8)        // 2376: pad 1 word per 8 -> lane
                                             // stride 9 (odd) -> conflict-free
#define WLEN    (2 * G + NTAPS - 1)          // 50-word per-thread window

__global__ __launch_bounds__(BLK)
__attribute__((amdgpu_waves_per_eu(4, 4)))
void poly_kernel(
    const float* __restrict__ x, const float* __restrict__ h,
    float* __restrict__ out, int n_out)
{
    __shared__ float xs[TILE_P];

    const int tid = threadIdx.x;
    const int b   = blockIdx.x;

    // Tile base: local group jl uses x[2*GPB*b + {21,22} + 2*jl - i];
    // tb = 2048b - 24 puts needed words at q = 45 + 2*jl - i in [3, 2093).
    const int tb = 2 * GROUPS_PER_BLK * b - 24;

    // Coalesced staging with zero-pad at edges. Logical word q lives at
    // p = q + (q>>3); a float4 at q%8 in {0,4} never straddles a pad.
    for (int q4 = tid; q4 < TILE_Q / 4; q4 += BLK) {
        const int gx = tb + 4 * q4;
        float4 v;
        if (gx >= 0 && gx + 3 < N_SIG) {
            v = *(const float4*)(x + gx);
        } else {
            v.x = (gx     >= 0 && gx     < N_SIG) ? x[gx]     : 0.0f;
            v.y = (gx + 1 >= 0 && gx + 1 < N_SIG) ? x[gx + 1] : 0.0f;
            v.z = (gx + 2 >= 0 && gx + 2 < N_SIG) ? x[gx + 2] : 0.0f;
            v.w = (gx + 3 >= 0 && gx + 3 < N_SIG) ? x[gx + 3] : 0.0f;
        }
        const int q = 4 * q4;
        const int p = q + (q >> 3);
        xs[p + 0] = v.x; xs[p + 1] = v.y; xs[p + 2] = v.z; xs[p + 3] = v.w;
    }
    __syncthreads();

    // Whole window in registers: w[k] = x_logical[8*tid + 3 + k], k in [0,50).
    // Padded word address: p = 9*tid + 3 + k + ((3+k)>>3)   (pad term is a
    // compile-time immediate per k; lane stride 9 words = odd = 2/bank, free).
    const float* __restrict__ wsrc = xs + 9 * tid + 3;
    float w[WLEN];
#pragma unroll
    for (int k = 0; k < WLEN; ++k)
        w[k] = wsrc[k + ((3 + k) >> 3)];

    float acc[3 * G];
#pragma unroll
    for (int k = 0; k < 3 * G; ++k) acc[k] = 0.0f;

    // Fully unrolled taps; all x operands are registers, h operands are
    // wave-uniform scalar loads (SGPR). Index map (derived, matches R1/R2):
    //   acc[3g+0] += w[42 + 2g - i] * h[3i+1]
    //   acc[3g+1] += w[43 + 2g - i] * h[3i+0]
    //   acc[3g+2] += w[43 + 2g - i] * h[3i+2]
#pragma unroll
    for (int i = 0; i < NTAPS; ++i) {
        const float h0 = h[3 * i + 0];
        const float h1 = h[3 * i + 1];
        const float h2 = h[3 * i + 2];
#pragma unroll
        for (int g = 0; g < G; ++g) {
            const float xa = w[(NTAPS - 1) + 2 * g - i];
            const float xb = w[NTAPS + 2 * g - i];
            acc[3 * g + 0] += xa * h1;
            acc[3 * g + 1] += xb * h0;
            acc[3 * g + 2] += xb * h2;
        }
    }

    // 12 contiguous outputs per thread (16B-aligned); fold the up=3 gain here.
    const int ob = 3 * GROUPS_PER_BLK * b + 3 * G * tid;
#pragma unroll
    for (int k = 0; k < 3; ++k) {
        if (ob + 4 * k + 3 < n_out) {
            *(float4*)(out + ob + 4 * k) =
                make_float4(3.0f * acc[4 * k + 0], 3.0f * acc[4 * k + 1],
                            3.0f * acc[4 * k + 2], 3.0f * acc[4 * k + 3]);
        }
    }
}

extern "C" void kernel_launch(void* const* d_in, const int* in_sizes, int n_in,
                              void* d_out, int out_size, void* d_ws, size_t ws_size,
                              hipStream_t stream) {
    const float* x = (const float*)d_in[0];
    const float* h = (const float*)d_in[1];
    float* out = (float*)d_out;
    const int blocks = (out_size + 3 * GROUPS_PER_BLK - 1) / (3 * GROUPS_PER_BLK);
    poly_kernel<<<blocks, BLK, 0, stream>>>(x, h, out, out_size);
}

// Round 3
// 78.354 us; speedup vs baseline: 1.4352x; 1.4352x over previous
//
#include <hip/hip_runtime.h>

// Polyphase resample up=3 down=2, N=2097152, L=129 taps, start=(L-1)/2=64.
// out[3j+0] = 3 * sum_i x[21+2j-i] * h[1+3i]   (i in [0,43))
// out[3j+1] = 3 * sum_i x[22+2j-i] * h[0+3i]
// out[3j+2] = 3 * sum_i x[22+2j-i] * h[2+3i]
// (formula verified: R1/R2 passed with absmax 0.25)
//
// R5 post-mortem of R3/R4: the 50-word register window was demoted to
// scratch (FETCH 77MB / WRITE 98MB vs ideal 8.4/12.6MB, VGPR=64) — most
// likely the 43-tap loop didn't fully unroll, leaving w[..-i] runtime-
// indexed => local memory (rule: runtime-indexed arrays go to scratch).
// waves_per_eu(4,4) changed nothing, so stop fighting the allocator:
// RESTRUCTURE window-word-major. For each of the 50 window words k
// (one ds_read each, stride-9 conflict-free), apply all of its <=12 FMA
// contributions immediately. Live set = acc[12] + 1 word + addressing
// ~= 25 VGPRs; no array exists to spill, robust to unroll decisions.
//
// Contribution map (inverse of the tap-major map, same 516 FMAs):
//   word k feeds  xa of tap ia = 42 + 2g - k  -> acc[3g+0] += wk * h[3*ia+1]
//                 xb of tap ib = 43 + 2g - k  -> acc[3g+1] += wk * h[3*ib+0]
//                                               acc[3g+2] += wk * h[3*ib+2]

#define N_SIG   2097152
#define L_FILT  129
#define NTAPS   43
#define G       4            // output groups per thread (12 outputs)
#define BLK     256
#define GROUPS_PER_BLK (BLK * G)             // 1024 groups -> 3072 outputs/block
#define TILE_Q  2112                         // logical tile words (covers q in [0,2093))
#define TILE_P  (TILE_Q + TILE_Q / 8)        // 2376: pad 1 word per 8 -> lane
                                             // stride 9 (odd) -> conflict-free
#define WLEN    (2 * G + NTAPS - 1)          // 50-word per-thread window

__global__ __launch_bounds__(BLK) void poly_kernel(
    const float* __restrict__ x, const float* __restrict__ h,
    float* __restrict__ out, int n_out)
{
    __shared__ float xs[TILE_P];

    const int tid = threadIdx.x;
    const int b   = blockIdx.x;

    // Tile base: local group jl uses x[2*GPB*b + {21,22} + 2*jl - i];
    // tb = 2048b - 24 puts needed words at q = 45 + 2*jl - i in [3, 2093).
    const int tb = 2 * GROUPS_PER_BLK * b - 24;

    // Coalesced staging with zero-pad at edges. Logical word q lives at
    // p = q + (q>>3); a float4 at q%8 in {0,4} never straddles a pad.
    for (int q4 = tid; q4 < TILE_Q / 4; q4 += BLK) {
        const int gx = tb + 4 * q4;
        float4 v;
        if (gx >= 0 && gx + 3 < N_SIG) {
            v = *(const float4*)(x + gx);
        } else {
            v.x = (gx     >= 0 && gx     < N_SIG) ? x[gx]     : 0.0f;
            v.y = (gx + 1 >= 0 && gx + 1 < N_SIG) ? x[gx + 1] : 0.0f;
            v.z = (gx + 2 >= 0 && gx + 2 < N_SIG) ? x[gx + 2] : 0.0f;
            v.w = (gx + 3 >= 0 && gx + 3 < N_SIG) ? x[gx + 3] : 0.0f;
        }
        const int q = 4 * q4;
        const int p = q + (q >> 3);
        xs[p + 0] = v.x; xs[p + 1] = v.y; xs[p + 2] = v.z; xs[p + 3] = v.w;
    }
    __syncthreads();

    float acc[3 * G];
#pragma unroll
    for (int k = 0; k < 3 * G; ++k) acc[k] = 0.0f;

    // Window word k lives at padded addr  9*tid + 3 + k + ((3+k)>>3);
    // the pad term is a compile-time immediate per k when unrolled.
    const float* __restrict__ wsrc = xs + 9 * tid + 3;

#pragma unroll
    for (int k = 0; k < WLEN; ++k) {
        const float wk = wsrc[k + ((3 + k) >> 3)];
#pragma unroll
        for (int g = 0; g < G; ++g) {
            const int ia = (NTAPS - 1) + 2 * g - k;   // xa tap
            const int ib = NTAPS + 2 * g - k;         // xb tap
            if (ia >= 0 && ia < NTAPS)
                acc[3 * g + 0] += wk * h[3 * ia + 1];
            if (ib >= 0 && ib < NTAPS) {
                acc[3 * g + 1] += wk * h[3 * ib + 0];
                acc[3 * g + 2] += wk * h[3 * ib + 2];
            }
        }
    }

    // 12 contiguous outputs per thread (16B-aligned); fold the up=3 gain here.
    const int ob = 3 * GROUPS_PER_BLK * b + 3 * G * tid;
#pragma unroll
    for (int k = 0; k < 3; ++k) {
        if (ob + 4 * k + 3 < n_out) {
            *(float4*)(out + ob + 4 * k) =
                make_float4(3.0f * acc[4 * k + 0], 3.0f * acc[4 * k + 1],
                            3.0f * acc[4 * k + 2], 3.0f * acc[4 * k + 3]);
        }
    }
}

extern "C" void kernel_launch(void* const* d_in, const int* in_sizes, int n_in,
                              void* d_out, int out_size, void* d_ws, size_t ws_size,
                              hipStream_t stream) {
    const float* x = (const float*)d_in[0];
    const float* h = (const float*)d_in[1];
    float* out = (float*)d_out;
    const int blocks = (out_size + 3 * GROUPS_PER_BLK - 1) / (3 * GROUPS_PER_BLK);
    poly_kernel<<<blocks, BLK, 0, stream>>>(x, h, out, out_size);
}